// Round 8
// baseline (196.107 us; speedup 1.0000x reference)
//
#include <hip/hip_runtime.h>
#include <math.h>

#define B 4
#define P 19248
#define C 81
#define M 32
#define K1 100
#define K2 15
#define G 32
#define HP 138
#define HO 550
#define FEPS 1e-6f

#define NBUCKET 8192   // bits >> 17; conf1 in (0,1) -> bucket < 8128
#define CAP 2048       // candidate cap

// iou tiling (round-4 proven config)
#define TI 16
#define NT 7
#define NTP 28
#define CH 128
#define NCH 8
#define SP 132

// ---- Stage 1: conf1 = softmax(conf)[:, :, 1], wave-per-row (R4-proven) ----
__global__ void k_conf1(const float* __restrict__ conf, float* __restrict__ conf1) {
    int gid  = blockIdx.x * blockDim.x + threadIdx.x;
    int wave = gid >> 6;
    int lane = threadIdx.x & 63;
    if (wave >= B * P) return;
    const float* row = conf + (size_t)wave * C;
    float x0 = (lane < C)      ? row[lane]      : -INFINITY;
    float x1 = (lane + 64 < C) ? row[lane + 64] : -INFINITY;
    float m = fmaxf(x0, x1);
#pragma unroll
    for (int o = 32; o; o >>= 1) m = fmaxf(m, __shfl_xor(m, o, 64));
    float s = 0.f;
    if (lane < C)      s += expf(x0 - m);
    if (lane + 64 < C) s += expf(x1 - m);
#pragma unroll
    for (int o = 32; o; o >>= 1) s += __shfl_xor(s, o, 64);
    if (lane == 0) conf1[wave] = expf(row[1] - m) / s;
}

// ---- Stage 2: hist + threshold + compact + rank + gather + buffer zeroing -
__global__ __launch_bounds__(1024) void k_select(
    const float* __restrict__ conf1, const float* __restrict__ loc,
    const float* __restrict__ mask,
    float* __restrict__ sconf, float* __restrict__ sloc, float* __restrict__ smask,
    float* __restrict__ Ibuf, float* __restrict__ Ubuf,
    float* __restrict__ acc, unsigned int* __restrict__ count) {
    int b = blockIdx.x;
    int tid = threadIdx.x;
    __shared__ unsigned int hist[NBUCKET];
    __shared__ unsigned int gsum_[1024];
    __shared__ unsigned int g2[64];
    __shared__ unsigned long long s_keys[CAP];
    __shared__ int s_T;
    __shared__ int s_cnt;
    __shared__ int   s_order[K1];
    __shared__ float s_conf[K1];

    // zero epilogue-targets early (no deps in this kernel)
    for (int i = tid; i < K1 * K1; i += 1024) {
        Ibuf[b * K1 * K1 + i] = 0.f;
        Ubuf[b * K1 * K1 + i] = 0.f;
    }
    if (b == 0 && tid == 0) { *acc = 0.f; *count = 0u; }

    for (int i = tid; i < NBUCKET; i += 1024) hist[i] = 0;
    if (tid == 0) s_cnt = 0;
    __syncthreads();

    // LDS histogram of conf1 bit-buckets
    for (int p = tid; p < P; p += 1024) {
        unsigned int bits = __float_as_uint(conf1[(size_t)b * P + p]);
        atomicAdd(&hist[bits >> 17], 1u);
    }
    __syncthreads();
    {
        unsigned int gs = 0;
#pragma unroll
        for (int i = 0; i < 8; ++i) gs += hist[tid * 8 + i];
        gsum_[tid] = gs;
    }
    __syncthreads();
    if (tid < 64) {
        unsigned int gs = 0;
#pragma unroll
        for (int i = 0; i < 16; ++i) gs += gsum_[tid * 16 + i];
        g2[tid] = gs;
    }
    __syncthreads();
    // parallel 3-level threshold scan (proven)
    if (tid < 64) {
        unsigned int v1 = g2[tid];
        unsigned int s1 = v1;
#pragma unroll
        for (int o = 1; o < 64; o <<= 1) {
            unsigned int x = __shfl_down(s1, o, 64);
            if (tid + o < 64) s1 += x;
        }
        unsigned long long m1 = __ballot((int)s1 >= K1);
        int S = 63 - __builtin_clzll(m1);
        int cum1 = (int)__shfl(s1, S, 64) - (int)__shfl(v1, S, 64);

        unsigned int v2 = (tid < 16) ? gsum_[S * 16 + tid] : 0u;
        unsigned int s2 = v2;
#pragma unroll
        for (int o = 1; o < 16; o <<= 1) {
            unsigned int x = __shfl_down(s2, o, 64);
            if (tid + o < 16) s2 += x;
        }
        unsigned long long m2 = __ballot((tid < 16) && (cum1 + (int)s2 >= K1));
        int r2 = 63 - __builtin_clzll(m2);
        int gI = S * 16 + r2;
        int cum2 = cum1 + (int)__shfl(s2, r2, 64) - (int)__shfl(v2, r2, 64);

        unsigned int v3 = (tid < 8) ? hist[gI * 8 + tid] : 0u;
        unsigned int s3 = v3;
#pragma unroll
        for (int o = 1; o < 8; o <<= 1) {
            unsigned int x = __shfl_down(s3, o, 64);
            if (tid + o < 8) s3 += x;
        }
        unsigned long long m3 = __ballot((tid < 8) && (cum2 + (int)s3 >= K1));
        int r3 = 63 - __builtin_clzll(m3);
        if (tid == 0) s_T = gI * 8 + r3;
    }
    __syncthreads();

    // compact candidates >= T into LDS
    int T = s_T;
    for (int p = tid; p < P; p += 1024) {
        unsigned int bits = __float_as_uint(conf1[(size_t)b * P + p]);
        if ((int)(bits >> 17) >= T) {
            int pos = atomicAdd(&s_cnt, 1);
            if (pos < CAP)
                s_keys[pos] = ((unsigned long long)bits << 32)
                            | (unsigned int)(0xFFFFFFFFu - (unsigned int)p);
        }
    }
    __syncthreads();
    int nc = min(s_cnt, CAP);
    int ncp = (nc + 7) & ~7;
    if (tid < ncp - nc) s_keys[nc + tid] = 0ULL;   // zero-pad for unroll
    __syncthreads();

    // exact rank by counting strictly-greater keys (keys unique)
    for (int t = tid; t < nc; t += 1024) {
        unsigned long long mk = s_keys[t];
        int rank = 0;
#pragma unroll 8
        for (int i = 0; i < ncp; ++i) rank += (s_keys[i] > mk);
        if (rank < K1) {
            s_order[rank] = (int)(0xFFFFFFFFu - (unsigned int)(mk & 0xFFFFFFFFu));
            s_conf[rank] = __uint_as_float((unsigned int)(mk >> 32));
        }
    }
    __syncthreads();

    for (int t = tid; t < K1; t += 1024) sconf[b * K1 + t] = s_conf[t];
    for (int t = tid; t < K1 * 4; t += 1024) {
        int k = t >> 2, d = t & 3;
        sloc[(b * K1 + k) * 4 + d] = loc[((size_t)b * P + s_order[k]) * 4 + d];
    }
    for (int t = tid; t < K1 * M; t += 1024) {
        int k = t >> 5, d = t & 31;
        smask[(b * K1 + k) * M + d] = mask[((size_t)b * P + s_order[k]) * M + d];
    }
}

// ---- Stage 3+4a: compute-staged gaussians + inter/union per pair ----------
// grid (NCH, NTP, B), 256 threads; gaussians computed in-place from sloc
// (bit-identical formula to the R4 k_gauss), pair sums atomicAdd to I/U.
__global__ __launch_bounds__(256) void k_iou(
    const float* __restrict__ sloc, float* __restrict__ Ibuf,
    float* __restrict__ Ubuf) {
    int ch = blockIdx.x;
    int tp = blockIdx.y;
    int b  = blockIdx.z;
    int ti = 0, rem = tp;
    while (rem >= NT - ti) { rem -= NT - ti; ++ti; }
    int tj = ti + rem;

    __shared__ __align__(16) float As[TI][SP];
    __shared__ __align__(16) float Bs[TI][SP];

    int tid = threadIdx.x;
    for (int idx = tid; idx < TI * (CH / 4); idx += 256) {
        int g = idx >> 5, v = idx & 31;
        int px0 = ch * CH + v * 4;
#pragma unroll
        for (int pass = 0; pass < 2; ++pass) {
            int gg = (pass ? tj : ti) * TI + g;
            float4 f = make_float4(0.f, 0.f, 0.f, 0.f);
            if (gg < K1) {
                const float* l = sloc + (b * K1 + gg) * 4;
                float cx = l[0], cy = l[1];
                float sx = fabsf(l[2]) * 0.5f + 0.001f;
                float sy = fabsf(l[3]) * 0.5f + 0.001f;
                float dsx = 2.f * sx * sx;
                float dsy = 2.f * sy * sy;
                float vals[4];
#pragma unroll
                for (int c = 0; c < 4; ++c) {
                    int px = px0 + c;
                    int y = px >> 5, x = px & 31;
                    float xs = (x + 0.5f) / (float)G;
                    float ys = (y + 0.5f) / (float)G;
                    float dx2 = (xs - cx) * (xs - cx) / dsx;
                    float dy2 = (ys - cy) * (ys - cy) / dsy;
                    vals[c] = expf(-(dy2 + dx2));
                }
                f = make_float4(vals[0], vals[1], vals[2], vals[3]);
            }
            if (pass) *(float4*)(&Bs[g][v * 4]) = f;
            else      *(float4*)(&As[g][v * 4]) = f;
        }
    }
    __syncthreads();

    int li = tid >> 4, lj = tid & 15;
    int i = ti * TI + li, j = tj * TI + lj;
    if (i < j && j < K1) {
        const float4* ar = (const float4*)(&As[li][0]);
        const float4* br = (const float4*)(&Bs[lj][0]);
        float inter = 0.f, uni = 0.f;
#pragma unroll
        for (int p = 0; p < CH / 4; ++p) {
            float4 a = ar[p], c = br[p];
            inter += fminf(a.x, c.x) + fminf(a.y, c.y)
                   + fminf(a.z, c.z) + fminf(a.w, c.w);
            uni   += fmaxf(a.x, c.x) + fmaxf(a.y, c.y)
                   + fmaxf(a.z, c.z) + fmaxf(a.w, c.w);
        }
        atomicAdd(&Ibuf[(b * K1 + i) * K1 + j], inter);
        atomicAdd(&Ubuf[(b * K1 + i) * K1 + j], uni);
    }
}

// ---- Stage 4b+5: iou max per column + keep-15 + gather (fused) ------------
__global__ __launch_bounds__(256) void k_nms(
    const float* __restrict__ Ibuf, const float* __restrict__ Ubuf,
    const float* __restrict__ sloc, const float* __restrict__ smask,
    const float* __restrict__ sconf,
    float* __restrict__ kloc, float* __restrict__ kmask,
    float* __restrict__ kconf) {
    int b = blockIdx.x;
    int tid = threadIdx.x;
    __shared__ unsigned int s_iomax[K1];
    __shared__ int s_keep[K2];
    for (int i = tid; i < K1; i += 256) s_iomax[i] = 0u;
    __syncthreads();
    for (int pr = tid; pr < K1 * K1; pr += 256) {
        int i = pr / K1, j = pr - (pr / K1) * K1;
        if (i < j) {
            float iou = Ibuf[b * K1 * K1 + pr] / Ubuf[b * K1 * K1 + pr];
            atomicMax(&s_iomax[j], __float_as_uint(iou));
        }
    }
    __syncthreads();
    if (tid < 64) {
        int lane = tid;
        float v0 = (lane < K1)      ? __uint_as_float(s_iomax[lane])      : INFINITY;
        float v1 = (lane + 64 < K1) ? __uint_as_float(s_iomax[lane + 64]) : INFINITY;
        for (int k = 0; k < K2; ++k) {
            float bv; int bi;
            if (v0 <= v1) { bv = v0; bi = lane; }
            else          { bv = v1; bi = lane + 64; }
#pragma unroll
            for (int o = 32; o; o >>= 1) {
                float ov = __shfl_xor(bv, o, 64);
                int   oi = __shfl_xor(bi, o, 64);
                if (ov < bv || (ov == bv && oi < bi)) { bv = ov; bi = oi; }
            }
            if (bi == lane)           v0 = INFINITY;
            else if (bi == lane + 64) v1 = INFINITY;
            if (lane == 0) s_keep[k] = bi;
        }
    }
    __syncthreads();
    for (int t = tid; t < K2 * M; t += 256) {
        int k = t >> 5, d = t & 31;
        kmask[(b * K2 + k) * M + d] = smask[(b * K1 + s_keep[k]) * M + d];
    }
    for (int t = tid; t < K2 * 4; t += 256) {
        int k = t >> 2, d = t & 3;
        kloc[(b * K2 + k) * 4 + d] = sloc[(b * K1 + s_keep[k]) * 4 + d];
    }
    if (tid < K2) kconf[b * K2 + tid] = sconf[b * K1 + s_keep[tid]];
}

// ---- Stage 6: final_conf at 138x138 (LDS-staged proto) --------------------
__global__ __launch_bounds__(256) void k_fconf(
    const float* __restrict__ proto, const float* __restrict__ kloc,
    const float* __restrict__ kmask, const float* __restrict__ kconf,
    float* __restrict__ fconf) {
    int b = blockIdx.y;
    int px0 = blockIdx.x * 256;
    int tid = threadIdx.x;
    __shared__ float s_pv[256][M + 1];
    __shared__ float s_km[K2][M];
    __shared__ float s_loc[K2][4];
    __shared__ float s_cf[K2];
    for (int t = tid; t < K2 * M; t += 256) s_km[t >> 5][t & 31] = kmask[b * K2 * M + t];
    for (int t = tid; t < K2 * 4; t += 256) s_loc[t >> 2][t & 3] = kloc[b * K2 * 4 + t];
    if (tid < K2) s_cf[tid] = kconf[b * K2 + tid];

    int nvalid = min(256, HP * HP - px0);
    const float4* pr4 = (const float4*)(proto + ((size_t)b * (HP * HP) + px0) * M);
    for (int idx = tid; idx < nvalid * (M / 4); idx += 256) {
        float4 f = pr4[idx];
        int q = idx >> 3, v = idx & 7;
        s_pv[q][v * 4 + 0] = f.x;
        s_pv[q][v * 4 + 1] = f.y;
        s_pv[q][v * 4 + 2] = f.z;
        s_pv[q][v * 4 + 3] = f.w;
    }
    __syncthreads();

    if (tid < nvalid) {
        int p = px0 + tid;
        int h = p / HP, w = p % HP;
        float pv[M];
#pragma unroll
        for (int m = 0; m < M; ++m) pv[m] = s_pv[tid][m];
        float ys = (h + 0.5f) / (float)HP;
        float xs = (w + 0.5f) / (float)HP;
        float sum_a = 0.f, sum_a2 = 0.f;
#pragma unroll 1
        for (int k = 0; k < K2; ++k) {
            float d = 0.f;
#pragma unroll
            for (int m = 0; m < M; ++m) d += pv[m] * s_km[k][m];
            float sig = 1.f / (1.f + expf(-d));
            float cx = s_loc[k][0], cy = s_loc[k][1];
            float sx = fabsf(s_loc[k][2]) * 0.5f + 0.001f;
            float sy = fabsf(s_loc[k][3]) * 0.5f + 0.001f;
            float dx2 = (xs - cx) * (xs - cx) / (2.f * sx * sx);
            float dy2 = (ys - cy) * (ys - cy) / (2.f * sy * sy);
            float ug = expf(-(dy2 + dx2));
            float a = sig * ug * s_cf[k];
            sum_a  += a;
            sum_a2 += a * a;
        }
        float fin = 1.f - sum_a2 / (sum_a + FEPS);
        if (!(fin == fin)) fin = 0.f;
        fconf[(size_t)b * HP * HP + p] = fin;
    }
}

// ---- Stage 7: resize+variance reduce, self-finalizing ---------------------
__global__ void k_reduce(const float* __restrict__ fconf, const float* __restrict__ original,
                         float* __restrict__ acc, unsigned int* __restrict__ count,
                         float* __restrict__ out) {
    int idx = blockIdx.x * 256 + threadIdx.x;
    float contrib = 0.f;
    if (idx < HO * HO) {
        int y = idx / HO, x = idx % HO;
        const float scale = (float)HP / (float)HO;
        float fy = (y + 0.5f) * scale - 0.5f;
        float fx = (x + 0.5f) * scale - 0.5f;
        float y0f = floorf(fy), x0f = floorf(fx);
        float wy = fy - y0f, wx = fx - x0f;
        int y0 = (int)y0f, x0 = (int)x0f;
        int iy0 = max(y0, 0), iy1 = min(y0 + 1, HP - 1);
        int ix0 = max(x0, 0), ix1 = min(x0 + 1, HP - 1);
        float r[B];
#pragma unroll
        for (int b = 0; b < B; ++b) {
            const float* F = fconf + (size_t)b * HP * HP;
            float v00 = F[iy0 * HP + ix0], v01 = F[iy0 * HP + ix1];
            float v10 = F[iy1 * HP + ix0], v11 = F[iy1 * HP + ix1];
            r[b] = (1.f - wy) * ((1.f - wx) * v00 + wx * v01)
                 +        wy  * ((1.f - wx) * v10 + wx * v11);
        }
        float t = r[0] + r[1] + r[2] + r[3];
        float s = 0.f;
#pragma unroll
        for (int c = 0; c < 3; ++c) {
            float o[B], wm = 0.f;
#pragma unroll
            for (int b = 0; b < B; ++b) {
                o[b] = original[(((size_t)b * 3 + c) * HO + y) * HO + x];
                wm += o[b] * r[b];
            }
#pragma unroll
            for (int b = 0; b < B; ++b) {
                float d = o[b] - wm;
                s += d * d * r[b];
            }
        }
        contrib = s / (t + FEPS);
    }
    __shared__ float red[256];
    red[threadIdx.x] = contrib;
    __syncthreads();
    for (int off = 128; off; off >>= 1) {
        if (threadIdx.x < off) red[threadIdx.x] += red[threadIdx.x + off];
        __syncthreads();
    }
    if (threadIdx.x == 0) {
        atomicAdd(acc, red[0]);
        __threadfence();
        unsigned int prev = atomicAdd(count, 1u);
        if (prev == gridDim.x - 1) {
            __threadfence();
            float total = atomicAdd(acc, 0.0f);
            out[0] = total / 100.f;
        }
    }
}

extern "C" void kernel_launch(void* const* d_in, const int* in_sizes, int n_in,
                              void* d_out, int out_size, void* d_ws, size_t ws_size,
                              hipStream_t stream) {
    (void)in_sizes; (void)n_in; (void)out_size; (void)ws_size;
    const float* original = (const float*)d_in[0];
    const float* loc      = (const float*)d_in[1];
    const float* conf     = (const float*)d_in[2];
    const float* mask     = (const float*)d_in[3];
    const float* proto    = (const float*)d_in[4];

    char* ws = (char*)d_ws;
    size_t off = 0;
    auto alloc = [&](size_t bytes) -> void* {
        void* p = ws + off;
        off += (bytes + 255) & ~(size_t)255;
        return p;
    };
    float* conf1        = (float*)alloc((size_t)B * P * sizeof(float));
    float* sconf        = (float*)alloc((size_t)B * K1 * sizeof(float));
    float* sloc         = (float*)alloc((size_t)B * K1 * 4 * sizeof(float));
    float* smask        = (float*)alloc((size_t)B * K1 * M * sizeof(float));
    float* Ibuf         = (float*)alloc((size_t)B * K1 * K1 * sizeof(float));
    float* Ubuf         = (float*)alloc((size_t)B * K1 * K1 * sizeof(float));
    float* kloc         = (float*)alloc((size_t)B * K2 * 4 * sizeof(float));
    float* kmask        = (float*)alloc((size_t)B * K2 * M * sizeof(float));
    float* kconf        = (float*)alloc((size_t)B * K2 * sizeof(float));
    float* fconf        = (float*)alloc((size_t)B * HP * HP * sizeof(float));
    float* acc          = (float*)alloc(sizeof(float));
    unsigned int* count = (unsigned int*)alloc(sizeof(unsigned int));

    // 6 dispatches, zero memsets (zeroing folded into k_select)
    k_conf1<<<(B * P) / 4, 256, 0, stream>>>(conf, conf1);
    k_select<<<B, 1024, 0, stream>>>(conf1, loc, mask, sconf, sloc, smask,
                                     Ibuf, Ubuf, acc, count);
    dim3 g4(NCH, NTP, B);
    k_iou<<<g4, 256, 0, stream>>>(sloc, Ibuf, Ubuf);
    k_nms<<<B, 256, 0, stream>>>(Ibuf, Ubuf, sloc, smask, sconf, kloc, kmask, kconf);
    dim3 g6((HP * HP + 255) / 256, B);
    k_fconf<<<g6, 256, 0, stream>>>(proto, kloc, kmask, kconf, fconf);
    k_reduce<<<(HO * HO + 255) / 256, 256, 0, stream>>>(fconf, original, acc, count,
                                                        (float*)d_out);
}

// Round 9
// 182.223 us; speedup vs baseline: 1.0762x; 1.0762x over previous
//
#include <hip/hip_runtime.h>
#include <math.h>

#define B 4
#define P 19248
#define C 81
#define M 32
#define K1 100
#define K2 15
#define G 32
#define HP 138
#define HO 550
#define FEPS 1e-6f

#define NBUCKET 8192   // bits >> 17; conf1 in (0,1) -> bucket < 8128
#define CAP 2048       // candidate cap

// iou tiling (round-4 proven config)
#define TI 16
#define NT 7
#define NTP 28
#define CH 128
#define NCH 8
#define SP 132

#define CR 128         // rows per conf1 block

// ---- Stage 1: conf1 = softmax(conf)[:, :, 1], float4-staged LDS -----------
// 128 rows/block staged as contiguous float4 (full 16B/lane coalescing);
// thread-per-row reduction from LDS (stride-81 = 2-way bank alias = free).
__global__ __launch_bounds__(128) void k_conf1(const float* __restrict__ conf,
                                               float* __restrict__ conf1) {
    int row0 = blockIdx.x * CR;
    int nrows = min(CR, B * P - row0);
    int tid = threadIdx.x;
    __shared__ float s_lin[CR * C];
    int nf4 = (nrows * C) >> 2;              // 128*81 and 64*81 both /4
    const float4* src = (const float4*)(conf + (size_t)row0 * C);
    float4* dst = (float4*)s_lin;
    for (int i = tid; i < nf4; i += 128) dst[i] = src[i];
    __syncthreads();
    if (tid < nrows) {
        const float* rw = &s_lin[tid * C];
        float m = rw[0];
#pragma unroll
        for (int i = 1; i < C; ++i) m = fmaxf(m, rw[i]);
        float s = 0.f, e1 = 0.f;
#pragma unroll
        for (int i = 0; i < C; ++i) {
            float e = expf(rw[i] - m);
            s += e;
            if (i == 1) e1 = e;
        }
        conf1[row0 + tid] = e1 / s;
    }
}

// ---- Stage 2: hist + threshold + compact + rank + gather + buffer zeroing -
__global__ __launch_bounds__(1024) void k_select(
    const float* __restrict__ conf1, const float* __restrict__ loc,
    const float* __restrict__ mask,
    float* __restrict__ sconf, float* __restrict__ sloc, float* __restrict__ smask,
    float* __restrict__ Ibuf, float* __restrict__ Ubuf,
    float* __restrict__ acc, unsigned int* __restrict__ count) {
    int b = blockIdx.x;
    int tid = threadIdx.x;
    __shared__ unsigned int hist[NBUCKET];
    __shared__ unsigned int gsum_[1024];
    __shared__ unsigned int g2[64];
    __shared__ unsigned long long s_keys[CAP];
    __shared__ int s_T;
    __shared__ int s_cnt;
    __shared__ int   s_order[K1];
    __shared__ float s_conf[K1];

    // zero epilogue-targets early (no deps in this kernel)
    for (int i = tid; i < K1 * K1; i += 1024) {
        Ibuf[b * K1 * K1 + i] = 0.f;
        Ubuf[b * K1 * K1 + i] = 0.f;
    }
    if (b == 0 && tid == 0) { *acc = 0.f; *count = 0u; }

    for (int i = tid; i < NBUCKET; i += 1024) hist[i] = 0;
    if (tid == 0) s_cnt = 0;
    __syncthreads();

    // LDS histogram of conf1 bit-buckets
    for (int p = tid; p < P; p += 1024) {
        unsigned int bits = __float_as_uint(conf1[(size_t)b * P + p]);
        atomicAdd(&hist[bits >> 17], 1u);
    }
    __syncthreads();
    {
        unsigned int gs = 0;
#pragma unroll
        for (int i = 0; i < 8; ++i) gs += hist[tid * 8 + i];
        gsum_[tid] = gs;
    }
    __syncthreads();
    if (tid < 64) {
        unsigned int gs = 0;
#pragma unroll
        for (int i = 0; i < 16; ++i) gs += gsum_[tid * 16 + i];
        g2[tid] = gs;
    }
    __syncthreads();
    // parallel 3-level threshold scan (proven)
    if (tid < 64) {
        unsigned int v1 = g2[tid];
        unsigned int s1 = v1;
#pragma unroll
        for (int o = 1; o < 64; o <<= 1) {
            unsigned int x = __shfl_down(s1, o, 64);
            if (tid + o < 64) s1 += x;
        }
        unsigned long long m1 = __ballot((int)s1 >= K1);
        int S = 63 - __builtin_clzll(m1);
        int cum1 = (int)__shfl(s1, S, 64) - (int)__shfl(v1, S, 64);

        unsigned int v2 = (tid < 16) ? gsum_[S * 16 + tid] : 0u;
        unsigned int s2 = v2;
#pragma unroll
        for (int o = 1; o < 16; o <<= 1) {
            unsigned int x = __shfl_down(s2, o, 64);
            if (tid + o < 16) s2 += x;
        }
        unsigned long long m2 = __ballot((tid < 16) && (cum1 + (int)s2 >= K1));
        int r2 = 63 - __builtin_clzll(m2);
        int gI = S * 16 + r2;
        int cum2 = cum1 + (int)__shfl(s2, r2, 64) - (int)__shfl(v2, r2, 64);

        unsigned int v3 = (tid < 8) ? hist[gI * 8 + tid] : 0u;
        unsigned int s3 = v3;
#pragma unroll
        for (int o = 1; o < 8; o <<= 1) {
            unsigned int x = __shfl_down(s3, o, 64);
            if (tid + o < 8) s3 += x;
        }
        unsigned long long m3 = __ballot((tid < 8) && (cum2 + (int)s3 >= K1));
        int r3 = 63 - __builtin_clzll(m3);
        if (tid == 0) s_T = gI * 8 + r3;
    }
    __syncthreads();

    // compact candidates >= T into LDS
    int T = s_T;
    for (int p = tid; p < P; p += 1024) {
        unsigned int bits = __float_as_uint(conf1[(size_t)b * P + p]);
        if ((int)(bits >> 17) >= T) {
            int pos = atomicAdd(&s_cnt, 1);
            if (pos < CAP)
                s_keys[pos] = ((unsigned long long)bits << 32)
                            | (unsigned int)(0xFFFFFFFFu - (unsigned int)p);
        }
    }
    __syncthreads();
    int nc = min(s_cnt, CAP);
    int ncp = (nc + 7) & ~7;
    if (tid < ncp - nc) s_keys[nc + tid] = 0ULL;   // zero-pad for unroll
    __syncthreads();

    // exact rank by counting strictly-greater keys (keys unique)
    for (int t = tid; t < nc; t += 1024) {
        unsigned long long mk = s_keys[t];
        int rank = 0;
#pragma unroll 8
        for (int i = 0; i < ncp; ++i) rank += (s_keys[i] > mk);
        if (rank < K1) {
            s_order[rank] = (int)(0xFFFFFFFFu - (unsigned int)(mk & 0xFFFFFFFFu));
            s_conf[rank] = __uint_as_float((unsigned int)(mk >> 32));
        }
    }
    __syncthreads();

    for (int t = tid; t < K1; t += 1024) sconf[b * K1 + t] = s_conf[t];
    for (int t = tid; t < K1 * 4; t += 1024) {
        int k = t >> 2, d = t & 3;
        sloc[(b * K1 + k) * 4 + d] = loc[((size_t)b * P + s_order[k]) * 4 + d];
    }
    for (int t = tid; t < K1 * M; t += 1024) {
        int k = t >> 5, d = t & 31;
        smask[(b * K1 + k) * M + d] = mask[((size_t)b * P + s_order[k]) * M + d];
    }
}

// ---- Stage 3+4a: compute-staged gaussians + inter/union per pair ----------
__global__ __launch_bounds__(256) void k_iou(
    const float* __restrict__ sloc, float* __restrict__ Ibuf,
    float* __restrict__ Ubuf) {
    int ch = blockIdx.x;
    int tp = blockIdx.y;
    int b  = blockIdx.z;
    int ti = 0, rem = tp;
    while (rem >= NT - ti) { rem -= NT - ti; ++ti; }
    int tj = ti + rem;

    __shared__ __align__(16) float As[TI][SP];
    __shared__ __align__(16) float Bs[TI][SP];

    int tid = threadIdx.x;
    for (int idx = tid; idx < TI * (CH / 4); idx += 256) {
        int g = idx >> 5, v = idx & 31;
        int px0 = ch * CH + v * 4;
#pragma unroll
        for (int pass = 0; pass < 2; ++pass) {
            int gg = (pass ? tj : ti) * TI + g;
            float4 f = make_float4(0.f, 0.f, 0.f, 0.f);
            if (gg < K1) {
                const float* l = sloc + (b * K1 + gg) * 4;
                float cx = l[0], cy = l[1];
                float sx = fabsf(l[2]) * 0.5f + 0.001f;
                float sy = fabsf(l[3]) * 0.5f + 0.001f;
                float dsx = 2.f * sx * sx;
                float dsy = 2.f * sy * sy;
                float vals[4];
#pragma unroll
                for (int c = 0; c < 4; ++c) {
                    int px = px0 + c;
                    int y = px >> 5, x = px & 31;
                    float xs = (x + 0.5f) / (float)G;
                    float ys = (y + 0.5f) / (float)G;
                    float dx2 = (xs - cx) * (xs - cx) / dsx;
                    float dy2 = (ys - cy) * (ys - cy) / dsy;
                    vals[c] = expf(-(dy2 + dx2));
                }
                f = make_float4(vals[0], vals[1], vals[2], vals[3]);
            }
            if (pass) *(float4*)(&Bs[g][v * 4]) = f;
            else      *(float4*)(&As[g][v * 4]) = f;
        }
    }
    __syncthreads();

    int li = tid >> 4, lj = tid & 15;
    int i = ti * TI + li, j = tj * TI + lj;
    if (i < j && j < K1) {
        const float4* ar = (const float4*)(&As[li][0]);
        const float4* br = (const float4*)(&Bs[lj][0]);
        float inter = 0.f, uni = 0.f;
#pragma unroll
        for (int p = 0; p < CH / 4; ++p) {
            float4 a = ar[p], c = br[p];
            inter += fminf(a.x, c.x) + fminf(a.y, c.y)
                   + fminf(a.z, c.z) + fminf(a.w, c.w);
            uni   += fmaxf(a.x, c.x) + fmaxf(a.y, c.y)
                   + fmaxf(a.z, c.z) + fmaxf(a.w, c.w);
        }
        atomicAdd(&Ibuf[(b * K1 + i) * K1 + j], inter);
        atomicAdd(&Ubuf[(b * K1 + i) * K1 + j], uni);
    }
}

// ---- Stage 4b+5: iou max per column + keep-15 + gather (fused) ------------
__global__ __launch_bounds__(256) void k_nms(
    const float* __restrict__ Ibuf, const float* __restrict__ Ubuf,
    const float* __restrict__ sloc, const float* __restrict__ smask,
    const float* __restrict__ sconf,
    float* __restrict__ kloc, float* __restrict__ kmask,
    float* __restrict__ kconf) {
    int b = blockIdx.x;
    int tid = threadIdx.x;
    __shared__ unsigned int s_iomax[K1];
    __shared__ int s_keep[K2];
    for (int i = tid; i < K1; i += 256) s_iomax[i] = 0u;
    __syncthreads();
    for (int pr = tid; pr < K1 * K1; pr += 256) {
        int i = pr / K1, j = pr - (pr / K1) * K1;
        if (i < j) {
            float iou = Ibuf[b * K1 * K1 + pr] / Ubuf[b * K1 * K1 + pr];
            atomicMax(&s_iomax[j], __float_as_uint(iou));
        }
    }
    __syncthreads();
    if (tid < 64) {
        int lane = tid;
        float v0 = (lane < K1)      ? __uint_as_float(s_iomax[lane])      : INFINITY;
        float v1 = (lane + 64 < K1) ? __uint_as_float(s_iomax[lane + 64]) : INFINITY;
        for (int k = 0; k < K2; ++k) {
            float bv; int bi;
            if (v0 <= v1) { bv = v0; bi = lane; }
            else          { bv = v1; bi = lane + 64; }
#pragma unroll
            for (int o = 32; o; o >>= 1) {
                float ov = __shfl_xor(bv, o, 64);
                int   oi = __shfl_xor(bi, o, 64);
                if (ov < bv || (ov == bv && oi < bi)) { bv = ov; bi = oi; }
            }
            if (bi == lane)           v0 = INFINITY;
            else if (bi == lane + 64) v1 = INFINITY;
            if (lane == 0) s_keep[k] = bi;
        }
    }
    __syncthreads();
    for (int t = tid; t < K2 * M; t += 256) {
        int k = t >> 5, d = t & 31;
        kmask[(b * K2 + k) * M + d] = smask[(b * K1 + s_keep[k]) * M + d];
    }
    for (int t = tid; t < K2 * 4; t += 256) {
        int k = t >> 2, d = t & 3;
        kloc[(b * K2 + k) * 4 + d] = sloc[(b * K1 + s_keep[k]) * 4 + d];
    }
    if (tid < K2) kconf[b * K2 + tid] = sconf[b * K1 + s_keep[tid]];
}

// ---- Stage 6: final_conf at 138x138 (LDS-staged proto) --------------------
__global__ __launch_bounds__(256) void k_fconf(
    const float* __restrict__ proto, const float* __restrict__ kloc,
    const float* __restrict__ kmask, const float* __restrict__ kconf,
    float* __restrict__ fconf) {
    int b = blockIdx.y;
    int px0 = blockIdx.x * 256;
    int tid = threadIdx.x;
    __shared__ float s_pv[256][M + 1];
    __shared__ float s_km[K2][M];
    __shared__ float s_loc[K2][4];
    __shared__ float s_cf[K2];
    for (int t = tid; t < K2 * M; t += 256) s_km[t >> 5][t & 31] = kmask[b * K2 * M + t];
    for (int t = tid; t < K2 * 4; t += 256) s_loc[t >> 2][t & 3] = kloc[b * K2 * 4 + t];
    if (tid < K2) s_cf[tid] = kconf[b * K2 + tid];

    int nvalid = min(256, HP * HP - px0);
    const float4* pr4 = (const float4*)(proto + ((size_t)b * (HP * HP) + px0) * M);
    for (int idx = tid; idx < nvalid * (M / 4); idx += 256) {
        float4 f = pr4[idx];
        int q = idx >> 3, v = idx & 7;
        s_pv[q][v * 4 + 0] = f.x;
        s_pv[q][v * 4 + 1] = f.y;
        s_pv[q][v * 4 + 2] = f.z;
        s_pv[q][v * 4 + 3] = f.w;
    }
    __syncthreads();

    if (tid < nvalid) {
        int p = px0 + tid;
        int h = p / HP, w = p % HP;
        float pv[M];
#pragma unroll
        for (int m = 0; m < M; ++m) pv[m] = s_pv[tid][m];
        float ys = (h + 0.5f) / (float)HP;
        float xs = (w + 0.5f) / (float)HP;
        float sum_a = 0.f, sum_a2 = 0.f;
#pragma unroll 1
        for (int k = 0; k < K2; ++k) {
            float d = 0.f;
#pragma unroll
            for (int m = 0; m < M; ++m) d += pv[m] * s_km[k][m];
            float sig = 1.f / (1.f + expf(-d));
            float cx = s_loc[k][0], cy = s_loc[k][1];
            float sx = fabsf(s_loc[k][2]) * 0.5f + 0.001f;
            float sy = fabsf(s_loc[k][3]) * 0.5f + 0.001f;
            float dx2 = (xs - cx) * (xs - cx) / (2.f * sx * sx);
            float dy2 = (ys - cy) * (ys - cy) / (2.f * sy * sy);
            float ug = expf(-(dy2 + dx2));
            float a = sig * ug * s_cf[k];
            sum_a  += a;
            sum_a2 += a * a;
        }
        float fin = 1.f - sum_a2 / (sum_a + FEPS);
        if (!(fin == fin)) fin = 0.f;
        fconf[(size_t)b * HP * HP + p] = fin;
    }
}

// ---- Stage 7: resize+variance reduce, 2 px/thread float2, self-finalizing -
__global__ __launch_bounds__(256) void k_reduce(
    const float* __restrict__ fconf, const float* __restrict__ original,
    float* __restrict__ acc, unsigned int* __restrict__ count,
    float* __restrict__ out) {
    int t2 = blockIdx.x * 256 + threadIdx.x;
    float contrib = 0.f;
    if (t2 < (HO * HO) / 2) {
        int px0 = t2 * 2;
        int y = px0 / HO;
        int x = px0 - y * HO;                  // even (HO even)
        const float scale = (float)HP / (float)HO;
        float fy = (y + 0.5f) * scale - 0.5f;
        float y0f = floorf(fy);
        float wy = fy - y0f;
        int y0 = (int)y0f;
        int iy0 = max(y0, 0), iy1 = min(y0 + 1, HP - 1);
        float r0[B], r1[B];
#pragma unroll
        for (int px = 0; px < 2; ++px) {
            float fx = (x + px + 0.5f) * scale - 0.5f;
            float x0f = floorf(fx);
            float wx = fx - x0f;
            int x0i = (int)x0f;
            int ix0 = max(x0i, 0), ix1 = min(x0i + 1, HP - 1);
#pragma unroll
            for (int b = 0; b < B; ++b) {
                const float* F = fconf + (size_t)b * HP * HP;
                float v00 = F[iy0 * HP + ix0], v01 = F[iy0 * HP + ix1];
                float v10 = F[iy1 * HP + ix0], v11 = F[iy1 * HP + ix1];
                float r = (1.f - wy) * ((1.f - wx) * v00 + wx * v01)
                        +        wy  * ((1.f - wx) * v10 + wx * v11);
                if (px) r1[b] = r; else r0[b] = r;
            }
        }
        float t0 = r0[0] + r0[1] + r0[2] + r0[3];
        float t1 = r1[0] + r1[1] + r1[2] + r1[3];
        float s0 = 0.f, s1 = 0.f;
#pragma unroll
        for (int c = 0; c < 3; ++c) {
            float2 o[B];
            float wm0 = 0.f, wm1 = 0.f;
#pragma unroll
            for (int b = 0; b < B; ++b) {
                o[b] = *(const float2*)(original + (((size_t)b * 3 + c) * HO + y) * HO + x);
                wm0 += o[b].x * r0[b];
                wm1 += o[b].y * r1[b];
            }
#pragma unroll
            for (int b = 0; b < B; ++b) {
                float d0 = o[b].x - wm0;
                float d1 = o[b].y - wm1;
                s0 += d0 * d0 * r0[b];
                s1 += d1 * d1 * r1[b];
            }
        }
        contrib = s0 / (t0 + FEPS) + s1 / (t1 + FEPS);
    }
    __shared__ float red[256];
    red[threadIdx.x] = contrib;
    __syncthreads();
    for (int off = 128; off; off >>= 1) {
        if (threadIdx.x < off) red[threadIdx.x] += red[threadIdx.x + off];
        __syncthreads();
    }
    if (threadIdx.x == 0) {
        atomicAdd(acc, red[0]);
        __threadfence();
        unsigned int prev = atomicAdd(count, 1u);
        if (prev == gridDim.x - 1) {
            __threadfence();
            float total = atomicAdd(acc, 0.0f);
            out[0] = total / 100.f;
        }
    }
}

extern "C" void kernel_launch(void* const* d_in, const int* in_sizes, int n_in,
                              void* d_out, int out_size, void* d_ws, size_t ws_size,
                              hipStream_t stream) {
    (void)in_sizes; (void)n_in; (void)out_size; (void)ws_size;
    const float* original = (const float*)d_in[0];
    const float* loc      = (const float*)d_in[1];
    const float* conf     = (const float*)d_in[2];
    const float* mask     = (const float*)d_in[3];
    const float* proto    = (const float*)d_in[4];

    char* ws = (char*)d_ws;
    size_t off = 0;
    auto alloc = [&](size_t bytes) -> void* {
        void* p = ws + off;
        off += (bytes + 255) & ~(size_t)255;
        return p;
    };
    float* conf1        = (float*)alloc((size_t)B * P * sizeof(float));
    float* sconf        = (float*)alloc((size_t)B * K1 * sizeof(float));
    float* sloc         = (float*)alloc((size_t)B * K1 * 4 * sizeof(float));
    float* smask        = (float*)alloc((size_t)B * K1 * M * sizeof(float));
    float* Ibuf         = (float*)alloc((size_t)B * K1 * K1 * sizeof(float));
    float* Ubuf         = (float*)alloc((size_t)B * K1 * K1 * sizeof(float));
    float* kloc         = (float*)alloc((size_t)B * K2 * 4 * sizeof(float));
    float* kmask        = (float*)alloc((size_t)B * K2 * M * sizeof(float));
    float* kconf        = (float*)alloc((size_t)B * K2 * sizeof(float));
    float* fconf        = (float*)alloc((size_t)B * HP * HP * sizeof(float));
    float* acc          = (float*)alloc(sizeof(float));
    unsigned int* count = (unsigned int*)alloc(sizeof(unsigned int));

    // 6 dispatches, zero memsets (zeroing folded into k_select)
    k_conf1<<<(B * P + CR - 1) / CR, 128, 0, stream>>>(conf, conf1);
    k_select<<<B, 1024, 0, stream>>>(conf1, loc, mask, sconf, sloc, smask,
                                     Ibuf, Ubuf, acc, count);
    dim3 g4(NCH, NTP, B);
    k_iou<<<g4, 256, 0, stream>>>(sloc, Ibuf, Ubuf);
    k_nms<<<B, 256, 0, stream>>>(Ibuf, Ubuf, sloc, smask, sconf, kloc, kmask, kconf);
    dim3 g6((HP * HP + 255) / 256, B);
    k_fconf<<<g6, 256, 0, stream>>>(proto, kloc, kmask, kconf, fconf);
    int nred = ((HO * HO) / 2 + 255) / 256;
    k_reduce<<<nred, 256, 0, stream>>>(fconf, original, acc, count, (float*)d_out);
}